// Round 4
// baseline (367.234 us; speedup 1.0000x reference)
//
#include <hip/hip_runtime.h>

// Problem constants (match reference)
constexpr int N    = 262144;   // rows
constexpr int C    = 1000;     // classes
constexpr int D    = 256;      // feature dim
constexpr int D4   = 64;       // float4s per row
constexpr int CPAD = 1024;     // padded class count (pow2 for scan/LDS)
constexpr int NB   = 64;       // histogram/scatter blocks
constexpr int ROWS_PER_B = N / NB;  // 4096
constexpr float ALPHA = 0.5f;

// Native vector type for nontemporal builtins (HIP_vector_type is rejected).
typedef float vfloat4 __attribute__((ext_vector_type(4)));

// ---------------- workspace layout (d_ws) ----------------
// int   hist       [NB][CPAD]   256 KB  (fully written by hist_kernel)
// int   counts     [CPAD]         4 KB
// int   blockcursor[NB][CPAD]   256 KB
// int   S          [N]            1 MB  packed (row<<10)|label, sorted by label
// float sums       [C*D]          1 MB  zeroed by hist_kernel
// No buffer is read before being fully written.

// 64 blocks x 256 threads; block b histograms rows [b*4096,(b+1)*4096).
// Also zeroes sums[] (grid-stride) since d_ws arrives poisoned 0xAA.
__global__ __launch_bounds__(256) void hist_kernel(
        const int* __restrict__ labels, int* __restrict__ hist,
        float4* __restrict__ sums4) {
    __shared__ int h[CPAD];
    int t = threadIdx.x;
    for (int i = t; i < CPAD; i += 256) h[i] = 0;
    // zero sums: C*D floats = 64000 float4s over 64 blocks x 256 threads
    for (int i = blockIdx.x * 256 + t; i < C * D / 4; i += NB * 256)
        sums4[i] = float4{0.f, 0.f, 0.f, 0.f};
    __syncthreads();
    int base = blockIdx.x * ROWS_PER_B;
    for (int i = t; i < ROWS_PER_B; i += 256)
        atomicAdd(&h[labels[base + i]], 1);
    __syncthreads();
    int* out = hist + blockIdx.x * CPAD;
    for (int i = t; i < CPAD; i += 256) out[i] = h[i];
}

// One block of 1024 threads (thread t = class t):
//  counts[t] = sum_b hist[b][t]; excl-scan over classes;
//  blockcursor[b][t] = scan[t] + prefix_b(hist[b][t]).
__global__ __launch_bounds__(1024) void scan_kernel(
        const int* __restrict__ hist,
        int* __restrict__ counts,
        int* __restrict__ blockcursor) {
    __shared__ int s[CPAD];
    int t = threadIdx.x;
    int total = 0;
    #pragma unroll 8
    for (int b = 0; b < NB; ++b) total += hist[b * CPAD + t];
    counts[t] = total;
    s[t] = total;
    __syncthreads();
    for (int off = 1; off < CPAD; off <<= 1) {
        int add = (t >= off) ? s[t - off] : 0;
        __syncthreads();
        s[t] += add;
        __syncthreads();
    }
    int run = s[t] - total;   // exclusive prefix over classes
    #pragma unroll 4
    for (int b = 0; b < NB; ++b) {
        blockcursor[b * CPAD + t] = run;
        run += hist[b * CPAD + t];
    }
}

// 64 blocks x 256 threads; LDS-private cursors -> zero global atomics.
// Writes packed (row<<10)|label into sorted position.
__global__ __launch_bounds__(256) void scatter_kernel(
        const int* __restrict__ labels,
        const int* __restrict__ blockcursor,
        int* __restrict__ S) {
    __shared__ int cur[CPAD];
    int t = threadIdx.x;
    const int* bc = blockcursor + blockIdx.x * CPAD;
    for (int i = t; i < CPAD; i += 256) cur[i] = bc[i];
    __syncthreads();
    int base = blockIdx.x * ROWS_PER_B;
    for (int i = t; i < ROWS_PER_B; i += 256) {
        int row = base + i;
        int lab = labels[row];
        int pos = atomicAdd(&cur[lab], 1);
        S[pos] = (row << 10) | lab;
    }
}

// 1024 blocks x 256 threads: block b reduces sorted slots [b*256,(b+1)*256).
// Each wave owns 64 consecutive slots; lane l covers dims [4l,4l+3].
// 8-deep software pipeline; wave-uniform class-boundary flushes via f32 atomics.
__global__ __launch_bounds__(256) void seg_reduce_kernel(
        const vfloat4* __restrict__ feat4,
        const int* __restrict__ S,
        float* __restrict__ sums) {
    int wave = threadIdx.x >> 6;
    int lane = threadIdx.x & 63;
    int base = (blockIdx.x * 4 + wave) * 64;   // this wave's 64 sorted slots
    int packed = S[base + lane];               // coalesced; slot i in lane i

    vfloat4 acc = (vfloat4)0.f;
    int cur = __shfl(packed, 0) & 1023;

    constexpr int PF = 8;
    int pk[PF];
    vfloat4 v[PF];
    #pragma unroll
    for (int j = 0; j < PF; ++j) {
        pk[j] = __shfl(packed, j);
        v[j]  = __builtin_nontemporal_load(&feat4[(long)(pk[j] >> 10) * D4 + lane]);
    }
    #pragma unroll
    for (int i = 0; i < 64; i += PF) {
        int npk[PF];
        vfloat4 nv[PF];
        if (i + PF < 64) {
            #pragma unroll
            for (int j = 0; j < PF; ++j) {
                npk[j] = __shfl(packed, i + PF + j);
                nv[j]  = __builtin_nontemporal_load(&feat4[(long)(npk[j] >> 10) * D4 + lane]);
            }
        }
        #pragma unroll
        for (int j = 0; j < PF; ++j) {
            int lab = pk[j] & 1023;
            if (lab != cur) {              // wave-uniform branch, rare (~2/wave)
                float* dst = sums + cur * D + lane * 4;
                unsafeAtomicAdd(dst + 0, acc.x);
                unsafeAtomicAdd(dst + 1, acc.y);
                unsafeAtomicAdd(dst + 2, acc.z);
                unsafeAtomicAdd(dst + 3, acc.w);
                acc = (vfloat4)0.f;
                cur = lab;
            }
            acc += v[j];
        }
        #pragma unroll
        for (int j = 0; j < PF; ++j) { pk[j] = npk[j]; v[j] = nv[j]; }
    }
    float* dst = sums + cur * D + lane * 4;
    unsafeAtomicAdd(dst + 0, acc.x);
    unsafeAtomicAdd(dst + 1, acc.y);
    unsafeAtomicAdd(dst + 2, acc.z);
    unsafeAtomicAdd(dst + 3, acc.w);
}

// EMA epilogue: one thread per float4 of the C x D output.
__global__ __launch_bounds__(256) void ema_kernel(
        const float4* __restrict__ cen4,
        const float* __restrict__ sums,
        const int* __restrict__ counts,
        float4* __restrict__ out4) {
    int idx = blockIdx.x * 256 + threadIdx.x;   // 0 .. C*64-1
    if (idx >= C * D4) return;
    int c = idx >> 6;
    int cnt = counts[c];
    float4 cen = cen4[idx];
    float4 o = cen;
    if (cnt > 0) {
        const float* sp = sums + c * D + (idx & 63) * 4;
        float s = ALPHA / (float)cnt;
        o.x = (1.0f - ALPHA) * cen.x + sp[0] * s;
        o.y = (1.0f - ALPHA) * cen.y + sp[1] * s;
        o.z = (1.0f - ALPHA) * cen.z + sp[2] * s;
        o.w = (1.0f - ALPHA) * cen.w + sp[3] * s;
    }
    out4[idx] = o;
}

extern "C" void kernel_launch(void* const* d_in, const int* in_sizes, int n_in,
                              void* d_out, int out_size, void* d_ws, size_t ws_size,
                              hipStream_t stream) {
    const vfloat4* feat4  = (const vfloat4*)d_in[0];
    const int*     labels = (const int*)d_in[1];
    const float4*  cen4   = (const float4*)d_in[2];
    float4*        out4   = (float4*)d_out;

    int*   hist        = (int*)d_ws;
    int*   counts      = hist + NB * CPAD;
    int*   blockcursor = counts + CPAD;
    int*   S           = blockcursor + NB * CPAD;
    float* sums        = (float*)(S + N);

    hist_kernel<<<NB, 256, 0, stream>>>(labels, hist, (float4*)sums);
    scan_kernel<<<1, CPAD, 0, stream>>>(hist, counts, blockcursor);
    scatter_kernel<<<NB, 256, 0, stream>>>(labels, blockcursor, S);
    seg_reduce_kernel<<<N / 256, 256, 0, stream>>>(feat4, S, sums);
    ema_kernel<<<(C * D4 + 255) / 256, 256, 0, stream>>>(cen4, sums, counts, out4);
}